// Round 1
// baseline (271.991 us; speedup 1.0000x reference)
//
#include <hip/hip_runtime.h>
#include <hip/hip_bf16.h>

typedef __attribute__((ext_vector_type(8))) short short8;   // 8 bf16 (4 VGPRs)
typedef __attribute__((ext_vector_type(4))) float f32x4;
typedef unsigned short u16;
typedef unsigned int u32;

#define SEQ 4096
#define NH 16
#define NKV 4

__device__ __forceinline__ u16 f2bf(float f) {
  return __builtin_bit_cast(u16, __float2bfloat16(f));
}

// ---------------- RoPE tables: cos/sin[pos][j], j=0..31 ----------------
__global__ __launch_bounds__(256) void k_tables(float* __restrict__ cosT,
                                                float* __restrict__ sinT) {
  int tid = blockIdx.x * 256 + threadIdx.x;   // SEQ*32
  int pos = tid >> 5, j = tid & 31;
  // theta = 1000^(-j/32) = 2^(-j*log2(1000)/32)
  float theta = exp2f(-0.311430758895f * (float)j);
  float a = (float)pos * theta;
  float s, c;
  sincosf(a, &s, &c);
  cosT[tid] = c;
  sinT[tid] = s;
}

// ---------------- x fp32 -> bf16 (vectorized) ----------------
__global__ __launch_bounds__(256) void k_convx(const float* __restrict__ x,
                                               u16* __restrict__ xb) {
  int i = blockIdx.x * 256 + threadIdx.x;     // one float4 each
  float4 v = ((const float4*)x)[i];
  u32 lo = (u32)f2bf(v.x) | ((u32)f2bf(v.y) << 16);
  u32 hi = (u32)f2bf(v.z) | ((u32)f2bf(v.w) << 16);
  uint2 o; o.x = lo; o.y = hi;
  ((uint2*)xb)[i] = o;
}

// ---------------- transpose + convert: dst[c][r] = bf16(src[r][c]) ----------------
// 64x64 tiles via padded LDS; R,C multiples of 64 in all uses.
__global__ __launch_bounds__(256) void k_tconv(const float* __restrict__ src, int sstride,
                                               u16* __restrict__ dst, int dstride) {
  __shared__ float tile[64][65];
  int br = blockIdx.y * 64, bc = blockIdx.x * 64;
  int t = threadIdx.x;
#pragma unroll
  for (int i = 0; i < 16; ++i) {
    int idx = t + i * 256;
    int r = idx >> 6, c = idx & 63;
    tile[r][c] = src[(long)(br + r) * sstride + bc + c];
  }
  __syncthreads();
#pragma unroll
  for (int i = 0; i < 16; ++i) {
    int idx = t + i * 256;
    int cc = idx >> 6, rr = idx & 63;
    dst[(long)(bc + cc) * dstride + br + rr] = f2bf(tile[rr][cc]);
  }
}

// ---------------- GEMM: C[M][N] f32 = A[M][K]bf16 * Bt[N][K]bf16^T ----------------
// 128x128 tile, BK=64, 4 waves (2x2), XOR-swizzled LDS, reg-staged prefetch.
__global__ __launch_bounds__(256) void k_gemm(const u16* __restrict__ A,
                                              const u16* __restrict__ Bt,
                                              float* __restrict__ C,
                                              int M, int N, int K) {
  __shared__ __align__(16) u16 a_lds[128 * 64];
  __shared__ __align__(16) u16 b_lds[128 * 64];
  const int bm = blockIdx.x * 128, bn = blockIdx.y * 128;
  const int t = threadIdx.x;
  const int l = t & 63, w = t >> 6;
  const int wm = (w >> 1) * 64, wn = (w & 1) * 64;
  const int lg = l >> 4, ll = l & 15;

  const f32x4 vzero = {0.f, 0.f, 0.f, 0.f};
  f32x4 acc[4][4];
#pragma unroll
  for (int i = 0; i < 4; ++i)
#pragma unroll
    for (int j = 0; j < 4; ++j) acc[i][j] = vzero;

  uint4 ar[4], brr[4];
#pragma unroll
  for (int i = 0; i < 4; ++i) {
    int ch = t + i * 256, r = ch >> 3, c = ch & 7;
    ar[i]  = *(const uint4*)(A  + (long)(bm + r) * K + c * 8);
    brr[i] = *(const uint4*)(Bt + (long)(bn + r) * K + c * 8);
  }
  for (int kt = 0;;) {
    __syncthreads();
#pragma unroll
    for (int i = 0; i < 4; ++i) {
      int ch = t + i * 256, r = ch >> 3, c = ch & 7;
      ((uint4*)a_lds)[r * 8 + (c ^ (r & 7))] = ar[i];
      ((uint4*)b_lds)[r * 8 + (c ^ (r & 7))] = brr[i];
    }
    __syncthreads();
    int ktn = kt + 64;
    if (ktn < K) {
#pragma unroll
      for (int i = 0; i < 4; ++i) {
        int ch = t + i * 256, r = ch >> 3, c = ch & 7;
        ar[i]  = *(const uint4*)(A  + (long)(bm + r) * K + ktn + c * 8);
        brr[i] = *(const uint4*)(Bt + (long)(bn + r) * K + ktn + c * 8);
      }
    }
#pragma unroll
    for (int kc = 0; kc < 2; ++kc) {
      short8 af[4], bfr[4];
#pragma unroll
      for (int mi = 0; mi < 4; ++mi) {
        int m = wm + mi * 16 + ll;
        af[mi] = *(const short8*)(a_lds + m * 64 + (((kc * 4 + lg) ^ (m & 7)) << 3));
      }
#pragma unroll
      for (int nb = 0; nb < 4; ++nb) {
        int n = wn + nb * 16 + ll;
        bfr[nb] = *(const short8*)(b_lds + n * 64 + (((kc * 4 + lg) ^ (n & 7)) << 3));
      }
#pragma unroll
      for (int mi = 0; mi < 4; ++mi)
#pragma unroll
        for (int nb = 0; nb < 4; ++nb)
          acc[mi][nb] = __builtin_amdgcn_mfma_f32_16x16x32_bf16(af[mi], bfr[nb],
                                                                acc[mi][nb], 0, 0, 0);
    }
    if (ktn >= K) break;
    kt = ktn;
  }
  const int rbase = bm + wm + lg * 4;
  const int cbase = bn + wn + ll;
#pragma unroll
  for (int mi = 0; mi < 4; ++mi)
#pragma unroll
    for (int nb = 0; nb < 4; ++nb)
#pragma unroll
      for (int r = 0; r < 4; ++r)
        C[(long)(rbase + mi * 16 + r) * N + cbase + nb * 16] = acc[mi][nb][r];
}

// ---------------- RoPE q: read qkv fp32, apply rope * 0.125, write q[h][pos][64] bf16 ----
__global__ __launch_bounds__(256) void k_ropeq(const float* __restrict__ qkv,
                                               const float* __restrict__ cosT,
                                               const float* __restrict__ sinT,
                                               u16* __restrict__ qb) {
  int tid = blockIdx.x * 256 + threadIdx.x;   // SEQ*NH*32
  int j = tid & 31, h = (tid >> 5) & 15, pos = tid >> 9;
  const float* row = qkv + (long)pos * 1536 + h * 64;
  float x1 = row[2 * j], x2 = row[2 * j + 1];
  float c = cosT[(pos << 5) + j], s = sinT[(pos << 5) + j];
  float e  = (x1 * c - x2 * s) * 0.125f;   // fold softmax scale 1/sqrt(64)
  float od = (x1 * s + x2 * c) * 0.125f;
  u32 pk = (u32)f2bf(e) | ((u32)f2bf(od) << 16);
  *(u32*)(qb + ((long)(h * SEQ + pos) * 64 + 2 * j)) = pk;
}

// ---------------- RoPE k: write k[kv][pos][64] bf16 (no scale) ----------------
__global__ __launch_bounds__(256) void k_ropek(const float* __restrict__ qkv,
                                               const float* __restrict__ cosT,
                                               const float* __restrict__ sinT,
                                               u16* __restrict__ kb) {
  int tid = blockIdx.x * 256 + threadIdx.x;   // SEQ*NKV*32
  int j = tid & 31, kv = (tid >> 5) & 3, pos = tid >> 7;
  const float* row = qkv + (long)pos * 1536 + 1024 + kv * 64;
  float x1 = row[2 * j], x2 = row[2 * j + 1];
  float c = cosT[(pos << 5) + j], s = sinT[(pos << 5) + j];
  float e  = (x1 * c - x2 * s);
  float od = (x1 * s + x2 * c);
  u32 pk = (u32)f2bf(e) | ((u32)f2bf(od) << 16);
  *(u32*)(kb + ((long)(kv * SEQ + pos) * 64 + 2 * j)) = pk;
}

// ---------------- Flash attention ----------------
// grid: 1024 blocks -> (h = b&15, qt = 63 - b>>4), 4 waves, 16 q-rows/wave.
// q pre-scaled by 1/8.  vT is [kv][d][seq].  o is [pos][h*64+d] bf16.
__global__ __launch_bounds__(256) void k_attn(const u16* __restrict__ q,
                                              const u16* __restrict__ k,
                                              const u16* __restrict__ vT,
                                              u16* __restrict__ o) {
  const int b = blockIdx.x;
  const int h = b & 15;
  const int qt = 63 - (b >> 4);
  const int hkv = h >> 2;
  __shared__ __align__(16) u16 k_lds[64 * 64];    // [k][d] swizzled
  __shared__ __align__(16) u16 vt_lds[64 * 64];   // [d][k] swizzled
  __shared__ __align__(16) u16 p_lds[4][16 * 64]; // per-wave [q][k] swizzled
  const int t = threadIdx.x, w = t >> 6, l = t & 63;
  const int lg = l >> 4, ll = l & 15;
  const int q0 = qt * 64 + w * 16;
  const f32x4 vzero = {0.f, 0.f, 0.f, 0.f};

  short8 qa0 = *(const short8*)(q + ((long)(h * SEQ + q0 + ll) * 64 + lg * 8));
  short8 qa1 = *(const short8*)(q + ((long)(h * SEQ + q0 + ll) * 64 + 32 + lg * 8));

  f32x4 Oacc[4];
#pragma unroll
  for (int i = 0; i < 4; ++i) Oacc[i] = vzero;
  float mrun[4], lrun[4];
#pragma unroll
  for (int r = 0; r < 4; ++r) { mrun[r] = -__builtin_inff(); lrun[r] = 0.f; }

  u16* pw = p_lds[w];

  for (int kt = 0; kt <= qt; ++kt) {
    __syncthreads();
#pragma unroll
    for (int i = 0; i < 2; ++i) {
      int ch = t + i * 256, r = ch >> 3, c = ch & 7;
      ((uint4*)k_lds)[r * 8 + (c ^ (r & 7))] =
          *(const uint4*)(k + ((long)(hkv * SEQ + kt * 64 + r) * 64 + c * 8));
      ((uint4*)vt_lds)[r * 8 + (c ^ (r & 7))] =
          *(const uint4*)(vT + ((long)(hkv * 64 + r) * SEQ + kt * 64 + c * 8));
    }
    __syncthreads();

    // QK^T: S[st] covers k-subtile st*16..st*16+15; rows = wave's 16 q.
    f32x4 S[4];
#pragma unroll
    for (int st = 0; st < 4; ++st) {
      int kr = st * 16 + ll;
      short8 b0 = *(const short8*)(k_lds + kr * 64 + ((lg ^ (kr & 7)) << 3));
      short8 b1 = *(const short8*)(k_lds + kr * 64 + (((4 + lg) ^ (kr & 7)) << 3));
      f32x4 z = vzero;
      z = __builtin_amdgcn_mfma_f32_16x16x32_bf16(qa0, b0, z, 0, 0, 0);
      z = __builtin_amdgcn_mfma_f32_16x16x32_bf16(qa1, b1, z, 0, 0, 0);
      S[st] = z;
    }
    if (kt == qt) {   // causal mask on diagonal block (block-relative indices)
#pragma unroll
      for (int st = 0; st < 4; ++st) {
        int kg = st * 16 + ll;
#pragma unroll
        for (int r = 0; r < 4; ++r)
          if (kg > w * 16 + lg * 4 + r) S[st][r] = -__builtin_inff();
      }
    }
    // online softmax: stats per q-row (row = lg*4+r, replicated over ll)
    float mnew[4], alpha[4];
#pragma unroll
    for (int r = 0; r < 4; ++r) {
      float m = fmaxf(fmaxf(S[0][r], S[1][r]), fmaxf(S[2][r], S[3][r]));
#pragma unroll
      for (int d = 1; d < 16; d <<= 1) m = fmaxf(m, __shfl_xor(m, d));
      mnew[r] = fmaxf(mrun[r], m);
      alpha[r] = __expf(mrun[r] - mnew[r]);
      mrun[r] = mnew[r];
      lrun[r] *= alpha[r];
    }
#pragma unroll
    for (int nb = 0; nb < 4; ++nb)
#pragma unroll
      for (int r = 0; r < 4; ++r) Oacc[nb][r] *= alpha[r];

    float rs[4] = {0.f, 0.f, 0.f, 0.f};
#pragma unroll
    for (int st = 0; st < 4; ++st) {
      int col = st * 16 + ll;
#pragma unroll
      for (int r = 0; r < 4; ++r) {
        float p = __expf(S[st][r] - mnew[r]);
        rs[r] += p;
        int row = lg * 4 + r;
        pw[row * 64 + ((((col >> 3) ^ (row & 7)) << 3) | (col & 7))] = f2bf(p);
      }
    }
#pragma unroll
    for (int r = 0; r < 4; ++r) {
      float v = rs[r];
#pragma unroll
      for (int d = 1; d < 16; d <<= 1) v += __shfl_xor(v, d);
      lrun[r] += v;
    }
    __syncthreads();   // p_lds visible (cross-lane within wave; keep safe)

    // PV: O[16q x 64d] += P[16x64] * V[64x64]
#pragma unroll
    for (int kc = 0; kc < 2; ++kc) {
      short8 pa = *(const short8*)(pw + ll * 64 + (((kc * 4 + lg) ^ (ll & 7)) << 3));
#pragma unroll
      for (int nb = 0; nb < 4; ++nb) {
        int d = nb * 16 + ll;
        short8 vb = *(const short8*)(vt_lds + d * 64 + (((kc * 4 + lg) ^ (d & 7)) << 3));
        Oacc[nb] = __builtin_amdgcn_mfma_f32_16x16x32_bf16(pa, vb, Oacc[nb], 0, 0, 0);
      }
    }
  }
  // epilogue: normalize and store bf16 to attn_out[pos][h*64+d]
#pragma unroll
  for (int nb = 0; nb < 4; ++nb) {
    int col = h * 64 + nb * 16 + ll;
#pragma unroll
    for (int r = 0; r < 4; ++r) {
      int row = q0 + lg * 4 + r;
      o[(long)row * 1024 + col] = f2bf(Oacc[nb][r] / lrun[r]);
    }
  }
}

extern "C" void kernel_launch(void* const* d_in, const int* in_sizes, int n_in,
                              void* d_out, int out_size, void* d_ws, size_t ws_size,
                              hipStream_t stream) {
  const float* x  = (const float*)d_in[0];
  // d_in[1] = mask (causal, implicit) — unused
  const float* Wq = (const float*)d_in[2];
  const float* Wk = (const float*)d_in[3];
  const float* Wv = (const float*)d_in[4];
  const float* Wo = (const float*)d_in[5];
  float* out = (float*)d_out;

  char* ws = (char*)d_ws;
  float* qkv = (float*)(ws);                        // 4096*1536*4  = 25165824
  u16* xb    = (u16*)(ws + 25165824);               // 4096*1024*2  = 8388608 (reused as attn_out)
  u16* Wt    = (u16*)(ws + 33554432);               // 1536*1024*2  = 3145728
  u16* Wto   = (u16*)(ws + 36700160);               // 1024*1024*2  = 2097152
  u16* qb    = (u16*)(ws + 38797312);               // 16*4096*64*2 = 8388608
  u16* kb    = (u16*)(ws + 47185920);               // 4*4096*64*2  = 2097152
  u16* vb    = (u16*)(ws + 49283072);               // 4*64*4096*2  = 2097152
  float* cosT = (float*)(ws + 51380224);            // 4096*32*4    = 524288
  float* sinT = (float*)(ws + 51904512);            // 524288  -> total 52428800 B

  k_tables<<<512, 256, 0, stream>>>(cosT, sinT);
  k_convx<<<4096, 256, 0, stream>>>(x, xb);
  k_tconv<<<dim3(16, 16), 256, 0, stream>>>(Wq, 1024, Wt, 1024);
  k_tconv<<<dim3(4, 16), 256, 0, stream>>>(Wk, 256, Wt + 1024 * 1024, 1024);
  k_tconv<<<dim3(4, 16), 256, 0, stream>>>(Wv, 256, Wt + 1280 * 1024, 1024);
  k_tconv<<<dim3(16, 16), 256, 0, stream>>>(Wo, 1024, Wto, 1024);

  // qkv = x @ [Wq|Wk|Wv]
  k_gemm<<<dim3(32, 12), 256, 0, stream>>>(xb, Wt, qkv, 4096, 1536, 1024);

  k_ropeq<<<8192, 256, 0, stream>>>(qkv, cosT, sinT, qb);
  k_ropek<<<2048, 256, 0, stream>>>(qkv, cosT, sinT, kb);
  for (int kv = 0; kv < 4; ++kv)   // v transposed: vb[kv][d][pos]
    k_tconv<<<dim3(1, 64), 256, 0, stream>>>(qkv + 1280 + kv * 64, 1536,
                                             vb + (long)kv * 64 * 4096, 4096);

  k_attn<<<1024, 256, 0, stream>>>(qb, kb, vb, xb);   // attn_out -> xb

  // out = attn_out @ Wo
  k_gemm<<<dim3(32, 8), 256, 0, stream>>>(xb, Wto, out, 4096, 1024, 1024);
}

// Round 2
// 231.058 us; speedup vs baseline: 1.1772x; 1.1772x over previous
//
#include <hip/hip_runtime.h>
#include <hip/hip_bf16.h>

typedef __attribute__((ext_vector_type(8))) short short8;   // 8 bf16 (4 VGPRs)
typedef __attribute__((ext_vector_type(4))) float f32x4;
typedef unsigned short u16;
typedef unsigned int u32;

#define SEQ 4096
#define NH 16
#define NKV 4

__device__ __forceinline__ u16 f2bf(float f) {
  return __builtin_bit_cast(u16, __float2bfloat16(f));
}

// ---------------- RoPE tables: cos/sin[pos][j], j=0..31 ----------------
__global__ __launch_bounds__(256) void k_tables(float* __restrict__ cosT,
                                                float* __restrict__ sinT) {
  int tid = blockIdx.x * 256 + threadIdx.x;   // SEQ*32
  int pos = tid >> 5, j = tid & 31;
  float theta = exp2f(-0.311430758895f * (float)j);  // 1000^(-j/32)
  float a = (float)pos * theta;
  float s, c;
  sincosf(a, &s, &c);
  cosT[tid] = c;
  sinT[tid] = s;
}

// ---------------- x fp32 -> bf16 (vectorized) ----------------
__global__ __launch_bounds__(256) void k_convx(const float* __restrict__ x,
                                               u16* __restrict__ xb) {
  int i = blockIdx.x * 256 + threadIdx.x;     // one float4 each
  float4 v = ((const float4*)x)[i];
  u32 lo = (u32)f2bf(v.x) | ((u32)f2bf(v.y) << 16);
  u32 hi = (u32)f2bf(v.z) | ((u32)f2bf(v.w) << 16);
  uint2 o; o.x = lo; o.y = hi;
  ((uint2*)xb)[i] = o;
}

// ---------------- transpose + convert: dst[c][r] = bf16(src[r][c]) ----------------
__global__ __launch_bounds__(256) void k_tconv(const float* __restrict__ src, int sstride,
                                               u16* __restrict__ dst, int dstride) {
  __shared__ float tile[64][65];
  int br = blockIdx.y * 64, bc = blockIdx.x * 64;
  int t = threadIdx.x;
#pragma unroll
  for (int i = 0; i < 16; ++i) {
    int idx = t + i * 256;
    int r = idx >> 6, c = idx & 63;
    tile[r][c] = src[(long)(br + r) * sstride + bc + c];
  }
  __syncthreads();
#pragma unroll
  for (int i = 0; i < 16; ++i) {
    int idx = t + i * 256;
    int cc = idx >> 6, rr = idx & 63;
    dst[(long)(bc + cc) * dstride + br + rr] = f2bf(tile[rr][cc]);
  }
}

// ---------------- GEMM: C[M][N] f32 = A[M][K]bf16 * Bt[N][K]bf16^T ----------------
__global__ __launch_bounds__(256) void k_gemm(const u16* __restrict__ A,
                                              const u16* __restrict__ Bt,
                                              float* __restrict__ C,
                                              int M, int N, int K) {
  __shared__ __align__(16) u16 a_lds[128 * 64];
  __shared__ __align__(16) u16 b_lds[128 * 64];
  const int bm = blockIdx.x * 128, bn = blockIdx.y * 128;
  const int t = threadIdx.x;
  const int l = t & 63, w = t >> 6;
  const int wm = (w >> 1) * 64, wn = (w & 1) * 64;
  const int lg = l >> 4, ll = l & 15;

  const f32x4 vzero = {0.f, 0.f, 0.f, 0.f};
  f32x4 acc[4][4];
#pragma unroll
  for (int i = 0; i < 4; ++i)
#pragma unroll
    for (int j = 0; j < 4; ++j) acc[i][j] = vzero;

  uint4 ar[4], brr[4];
#pragma unroll
  for (int i = 0; i < 4; ++i) {
    int ch = t + i * 256, r = ch >> 3, c = ch & 7;
    ar[i]  = *(const uint4*)(A  + (long)(bm + r) * K + c * 8);
    brr[i] = *(const uint4*)(Bt + (long)(bn + r) * K + c * 8);
  }
  for (int kt = 0;;) {
    __syncthreads();
#pragma unroll
    for (int i = 0; i < 4; ++i) {
      int ch = t + i * 256, r = ch >> 3, c = ch & 7;
      ((uint4*)a_lds)[r * 8 + (c ^ (r & 7))] = ar[i];
      ((uint4*)b_lds)[r * 8 + (c ^ (r & 7))] = brr[i];
    }
    __syncthreads();
    int ktn = kt + 64;
    if (ktn < K) {
#pragma unroll
      for (int i = 0; i < 4; ++i) {
        int ch = t + i * 256, r = ch >> 3, c = ch & 7;
        ar[i]  = *(const uint4*)(A  + (long)(bm + r) * K + ktn + c * 8);
        brr[i] = *(const uint4*)(Bt + (long)(bn + r) * K + ktn + c * 8);
      }
    }
#pragma unroll
    for (int kc = 0; kc < 2; ++kc) {
      short8 af[4], bfr[4];
#pragma unroll
      for (int mi = 0; mi < 4; ++mi) {
        int m = wm + mi * 16 + ll;
        af[mi] = *(const short8*)(a_lds + m * 64 + (((kc * 4 + lg) ^ (m & 7)) << 3));
      }
#pragma unroll
      for (int nb = 0; nb < 4; ++nb) {
        int n = wn + nb * 16 + ll;
        bfr[nb] = *(const short8*)(b_lds + n * 64 + (((kc * 4 + lg) ^ (n & 7)) << 3));
      }
#pragma unroll
      for (int mi = 0; mi < 4; ++mi)
#pragma unroll
        for (int nb = 0; nb < 4; ++nb)
          acc[mi][nb] = __builtin_amdgcn_mfma_f32_16x16x32_bf16(af[mi], bfr[nb],
                                                                acc[mi][nb], 0, 0, 0);
    }
    if (ktn >= K) break;
    kt = ktn;
  }
  const int rbase = bm + wm + lg * 4;
  const int cbase = bn + wn + ll;
#pragma unroll
  for (int mi = 0; mi < 4; ++mi)
#pragma unroll
    for (int nb = 0; nb < 4; ++nb)
#pragma unroll
      for (int r = 0; r < 4; ++r)
        C[(long)(rbase + mi * 16 + r) * N + cbase + nb * 16] = acc[mi][nb][r];
}

// ---------------- fused RoPE for q and k ----------------
// grid (512, 20): blockIdx.y < 16 -> q head (scale folds 1/8 * log2(e)); else kv head.
__global__ __launch_bounds__(256) void k_rope(const float* __restrict__ qkv,
                                              const float* __restrict__ cosT,
                                              const float* __restrict__ sinT,
                                              u16* __restrict__ qb,
                                              u16* __restrict__ kb) {
  int j = threadIdx.x & 31;
  int pos = blockIdx.x * 8 + (threadIdx.x >> 5);
  int he = blockIdx.y;
  const float* row;
  float scale;
  u16* dst;
  if (he < 16) {
    row = qkv + (long)pos * 1536 + he * 64;
    scale = 0.18033688011112042f;          // 0.125 * log2(e): softmax in log2 domain
    dst = qb + (long)(he * SEQ + pos) * 64;
  } else {
    int kv = he - 16;
    row = qkv + (long)pos * 1536 + 1024 + kv * 64;
    scale = 1.0f;
    dst = kb + (long)(kv * SEQ + pos) * 64;
  }
  float x1 = row[2 * j], x2 = row[2 * j + 1];
  float c = cosT[(pos << 5) + j], s = sinT[(pos << 5) + j];
  float e  = (x1 * c - x2 * s) * scale;
  float od = (x1 * s + x2 * c) * scale;
  *(u32*)(dst + 2 * j) = (u32)f2bf(e) | ((u32)f2bf(od) << 16);
}

// ---------------- Flash attention (swapped QK^T, async stage, defer-max) ----------
// grid: 1024 blocks -> (h = b&15, qt = 63 - b>>4), 4 waves, 16 q-rows/wave.
// q pre-scaled by 0.125*log2e (softmax in log2 domain). vT is [kv][d][seq].
__global__ __launch_bounds__(256) void k_attn(const u16* __restrict__ q,
                                              const u16* __restrict__ k,
                                              const u16* __restrict__ vT,
                                              u16* __restrict__ o) {
  const int b = blockIdx.x;
  const int h = b & 15;
  const int qt = 63 - (b >> 4);
  const int hkv = h >> 2;
  __shared__ __align__(16) u16 kbuf[2][64 * 64];
  __shared__ __align__(16) u16 vbuf[2][64 * 64];
  __shared__ __align__(16) u16 p_lds[4][16 * 64];
  const int t = threadIdx.x, w = t >> 6, l = t & 63;
  const int lg = l >> 4, ll = l & 15;
  const int q0 = qt * 64 + w * 16;
  const f32x4 vzero = {0.f, 0.f, 0.f, 0.f};

  short8 qa0 = *(const short8*)(q + ((long)(h * SEQ + q0 + ll) * 64 + lg * 8));
  short8 qa1 = *(const short8*)(q + ((long)(h * SEQ + q0 + ll) * 64 + 32 + lg * 8));

  f32x4 Oacc[4];
#pragma unroll
  for (int i = 0; i < 4; ++i) Oacc[i] = vzero;
  float mrun = -__builtin_inff();   // per-lane stats for q-row = ll (log2 domain)
  float lrun = 0.f;

  const u16* kbase = k + (long)hkv * SEQ * 64;
  const u16* vbase = vT + (long)hkv * 64 * SEQ;
  const int sr0 = t >> 3, sc = t & 7, sr1 = sr0 + 32;

  uint4 kr0, kr1, vr0, vr1;
#define ISSUE(KT)                                                            \
  {                                                                          \
    long kc0 = (long)(KT) * 64;                                              \
    kr0 = *(const uint4*)(kbase + (kc0 + sr0) * 64 + sc * 8);                \
    kr1 = *(const uint4*)(kbase + (kc0 + sr1) * 64 + sc * 8);                \
    vr0 = *(const uint4*)(vbase + (long)sr0 * SEQ + kc0 + sc * 8);           \
    vr1 = *(const uint4*)(vbase + (long)sr1 * SEQ + kc0 + sc * 8);           \
  }

  ISSUE(0);
  u16* pw = p_lds[w];

  for (int kt = 0; kt <= qt; ++kt) {
    u16* kc_ = kbuf[kt & 1];
    u16* vc_ = vbuf[kt & 1];
    ((uint4*)kc_)[sr0 * 8 + (sc ^ (sr0 & 7))] = kr0;
    ((uint4*)kc_)[sr1 * 8 + (sc ^ (sr1 & 7))] = kr1;
    ((uint4*)vc_)[sr0 * 8 + (sc ^ (sr0 & 7))] = vr0;
    ((uint4*)vc_)[sr1 * 8 + (sc ^ (sr1 & 7))] = vr1;
    if (kt < qt) ISSUE(kt + 1);
    __syncthreads();

    // QK^T swapped: S^T = mfma(A=K, B=Q) -> lane holds S[q=ll][key=st*16+lg*4+r]
    f32x4 S[4];
    __builtin_amdgcn_s_setprio(1);
#pragma unroll
    for (int st = 0; st < 4; ++st) {
      int kr_ = st * 16 + ll;
      short8 ka0 = *(const short8*)(kc_ + kr_ * 64 + ((lg ^ (kr_ & 7)) << 3));
      short8 ka1 = *(const short8*)(kc_ + kr_ * 64 + (((4 + lg) ^ (kr_ & 7)) << 3));
      f32x4 z = vzero;
      z = __builtin_amdgcn_mfma_f32_16x16x32_bf16(ka0, qa0, z, 0, 0, 0);
      z = __builtin_amdgcn_mfma_f32_16x16x32_bf16(ka1, qa1, z, 0, 0, 0);
      S[st] = z;
    }
    __builtin_amdgcn_s_setprio(0);

    if (kt == qt) {   // causal mask on diagonal block (block-relative)
#pragma unroll
      for (int st = 0; st < 4; ++st)
#pragma unroll
        for (int r = 0; r < 4; ++r)
          if (st * 16 + lg * 4 + r > w * 16 + ll) S[st][r] = -__builtin_inff();
    }

    // per-lane row max (q=ll): 16 local + reduce over lg groups
    float ml = S[0][0];
#pragma unroll
    for (int st = 0; st < 4; ++st)
#pragma unroll
      for (int r = 0; r < 4; ++r) ml = fmaxf(ml, S[st][r]);
    ml = fmaxf(ml, __shfl_xor(ml, 16));
    ml = fmaxf(ml, __shfl_xor(ml, 32));

    if (__any(ml > mrun + 8.f)) {   // defer-max: rescale only when needed
      float mnew = fmaxf(mrun, ml);
      float alpha = exp2f(mrun - mnew);
      mrun = mnew;
      lrun *= alpha;
      float ar_[4];
#pragma unroll
      for (int r = 0; r < 4; ++r) ar_[r] = __shfl(alpha, (l & 48) | (lg * 4 + r));
#pragma unroll
      for (int nb = 0; nb < 4; ++nb)
#pragma unroll
        for (int r = 0; r < 4; ++r) Oacc[nb][r] *= ar_[r];
    }

    float p[4][4];
    float sl = 0.f;
#pragma unroll
    for (int st = 0; st < 4; ++st)
#pragma unroll
      for (int r = 0; r < 4; ++r) {
        p[st][r] = exp2f(S[st][r] - mrun);
        sl += p[st][r];
      }
    sl += __shfl_xor(sl, 16);
    sl += __shfl_xor(sl, 32);
    lrun += sl;

    // pack P -> bf16, 4x ds_write_b64 into per-wave swizzled [16][64]
#pragma unroll
    for (int st = 0; st < 4; ++st) {
      u32 g0 = (u32)f2bf(p[st][0]) | ((u32)f2bf(p[st][1]) << 16);
      u32 g1 = (u32)f2bf(p[st][2]) | ((u32)f2bf(p[st][3]) << 16);
      int c16 = (st * 2 + (lg >> 1)) ^ (ll & 7);
      uint2 gg; gg.x = g0; gg.y = g1;
      ((uint2*)pw)[ll * 16 + c16 * 2 + (lg & 1)] = gg;
    }

    // PV: O[16q x 64d] += P[16x64] * V[64x64]
    __builtin_amdgcn_s_setprio(1);
#pragma unroll
    for (int kc = 0; kc < 2; ++kc) {
      short8 pa = *(const short8*)(pw + ll * 64 + (((kc * 4 + lg) ^ (ll & 7)) << 3));
#pragma unroll
      for (int nb = 0; nb < 4; ++nb) {
        int d = nb * 16 + ll;
        short8 vb = *(const short8*)(vc_ + d * 64 + (((kc * 4 + lg) ^ (d & 7)) << 3));
        Oacc[nb] = __builtin_amdgcn_mfma_f32_16x16x32_bf16(pa, vb, Oacc[nb], 0, 0, 0);
      }
    }
    __builtin_amdgcn_s_setprio(0);
  }
#undef ISSUE

  // epilogue: bring l back to O-row layout, normalize, store bf16
  float lr_[4];
#pragma unroll
  for (int r = 0; r < 4; ++r) lr_[r] = 1.f / __shfl(lrun, (l & 48) | (lg * 4 + r));
#pragma unroll
  for (int nb = 0; nb < 4; ++nb) {
    int col = h * 64 + nb * 16 + ll;
#pragma unroll
    for (int r = 0; r < 4; ++r) {
      int row = q0 + lg * 4 + r;
      o[(long)row * 1024 + col] = f2bf(Oacc[nb][r] * lr_[r]);
    }
  }
}

extern "C" void kernel_launch(void* const* d_in, const int* in_sizes, int n_in,
                              void* d_out, int out_size, void* d_ws, size_t ws_size,
                              hipStream_t stream) {
  const float* x  = (const float*)d_in[0];
  // d_in[1] = mask (causal, implicit) — unused
  const float* Wq = (const float*)d_in[2];
  const float* Wk = (const float*)d_in[3];
  const float* Wv = (const float*)d_in[4];
  const float* Wo = (const float*)d_in[5];
  float* out = (float*)d_out;

  char* ws = (char*)d_ws;
  float* qkv = (float*)(ws);                        // 4096*1536*4  = 25165824
  u16* xb    = (u16*)(ws + 25165824);               // 4096*1024*2  = 8388608 (reused as attn_out)
  u16* Wt    = (u16*)(ws + 33554432);               // 1536*1024*2  = 3145728
  u16* Wto   = (u16*)(ws + 36700160);               // 1024*1024*2  = 2097152
  u16* qb    = (u16*)(ws + 38797312);               // 16*4096*64*2 = 8388608
  u16* kb    = (u16*)(ws + 47185920);               // 4*4096*64*2  = 2097152
  u16* vb    = (u16*)(ws + 49283072);               // 4*64*4096*2  = 2097152
  float* cosT = (float*)(ws + 51380224);            // 4096*32*4    = 524288
  float* sinT = (float*)(ws + 51904512);            // 524288  -> total 52428800 B

  k_tables<<<512, 256, 0, stream>>>(cosT, sinT);
  k_convx<<<4096, 256, 0, stream>>>(x, xb);
  k_tconv<<<dim3(16, 16), 256, 0, stream>>>(Wq, 1024, Wt, 1024);
  k_tconv<<<dim3(4, 16), 256, 0, stream>>>(Wk, 256, Wt + 1024 * 1024, 1024);
  k_tconv<<<dim3(4, 16), 256, 0, stream>>>(Wv, 256, Wt + 1280 * 1024, 1024);
  k_tconv<<<dim3(16, 16), 256, 0, stream>>>(Wo, 1024, Wto, 1024);

  // qkv = x @ [Wq|Wk|Wv]
  k_gemm<<<dim3(32, 12), 256, 0, stream>>>(xb, Wt, qkv, 4096, 1536, 1024);

  // RoPE q+k fused (q scale folds 0.125*log2e)
  k_rope<<<dim3(512, 20), 256, 0, stream>>>(qkv, cosT, sinT, qb, kb);
  // v transposed: vb[kv][d][pos] — single launch over the 4096x256 V block
  k_tconv<<<dim3(4, 64), 256, 0, stream>>>(qkv + 1280, 1536, vb, 4096);

  k_attn<<<1024, 256, 0, stream>>>(qb, kb, vb, xb);   // attn_out -> xb

  // out = attn_out @ Wo
  k_gemm<<<dim3(32, 8), 256, 0, stream>>>(xb, Wto, out, 4096, 1024, 1024);
}

// Round 3
// 172.710 us; speedup vs baseline: 1.5748x; 1.3378x over previous
//
#include <hip/hip_runtime.h>
#include <hip/hip_bf16.h>

typedef __attribute__((ext_vector_type(8))) short short8;   // 8 bf16 (4 VGPRs)
typedef __attribute__((ext_vector_type(4))) float f32x4;
typedef unsigned short u16;
typedef unsigned int u32;

#define SEQ 4096

__device__ __forceinline__ u16 f2bf(float f) {
  return __builtin_bit_cast(u16, __float2bfloat16(f));
}

// global -> LDS direct (16B/lane). LDS dest = wave-uniform base + lane*16.
typedef __attribute__((address_space(1))) u32 gas_u32;
typedef __attribute__((address_space(3))) u32 las_u32;
__device__ __forceinline__ void gload16(const u16* g, const u16* l) {
  __builtin_amdgcn_global_load_lds((gas_u32*)(unsigned long long)(const void*)g,
                                   (las_u32*)(u32)(unsigned long long)(const void*)l,
                                   16, 0, 0);
}

// ---------------- RoPE tables: cos/sin[pos][j], j=0..31 ----------------
__global__ __launch_bounds__(256) void k_tables(float* __restrict__ cosT,
                                                float* __restrict__ sinT) {
  int tid = blockIdx.x * 256 + threadIdx.x;   // SEQ*32
  int pos = tid >> 5, j = tid & 31;
  float theta = exp2f(-0.311430758895f * (float)j);  // 1000^(-j/32)
  float a = (float)pos * theta;
  float s, c;
  sincosf(a, &s, &c);
  cosT[tid] = c;
  sinT[tid] = s;
}

// ---------------- x fp32 -> bf16 (vectorized) ----------------
__global__ __launch_bounds__(256) void k_convx(const float* __restrict__ x,
                                               u16* __restrict__ xb) {
  int i = blockIdx.x * 256 + threadIdx.x;     // one float4 each
  float4 v = ((const float4*)x)[i];
  u32 lo = (u32)f2bf(v.x) | ((u32)f2bf(v.y) << 16);
  u32 hi = (u32)f2bf(v.z) | ((u32)f2bf(v.w) << 16);
  uint2 o; o.x = lo; o.y = hi;
  ((uint2*)xb)[i] = o;
}

// ---------------- transpose + convert: dst[c][r] = bf16(src[r][c]) ----------------
__global__ __launch_bounds__(256) void k_tconv(const float* __restrict__ src, int sstride,
                                               u16* __restrict__ dst, int dstride) {
  __shared__ float tile[64][65];
  int br = blockIdx.y * 64, bc = blockIdx.x * 64;
  int t = threadIdx.x;
#pragma unroll
  for (int i = 0; i < 16; ++i) {
    int idx = t + i * 256;
    int r = idx >> 6, c = idx & 63;
    tile[r][c] = src[(long)(br + r) * sstride + bc + c];
  }
  __syncthreads();
#pragma unroll
  for (int i = 0; i < 16; ++i) {
    int idx = t + i * 256;
    int cc = idx >> 6, rr = idx & 63;
    dst[(long)(bc + cc) * dstride + br + rr] = f2bf(tile[rr][cc]);
  }
}

// ---------------- GEMM: C[M][N] f32 = A[M][K]bf16 * Bt[N][K]bf16^T ----------------
// m97 structure: 128x128 tile, BK=64, linear LDS, global_load_lds width-16,
// single buffer + 2 barriers per K-step.
__global__ __launch_bounds__(256) void k_gemm(const u16* __restrict__ A,
                                              const u16* __restrict__ Bt,
                                              float* __restrict__ C,
                                              int M, int N, int K) {
  __shared__ __align__(16) u16 a_lds[128 * 64];
  __shared__ __align__(16) u16 b_lds[128 * 64];
  const int bm = blockIdx.x * 128, bn = blockIdx.y * 128;
  const int t = threadIdx.x;
  const int l = t & 63, w = t >> 6;
  const int wm = (w >> 1) * 64, wn = (w & 1) * 64;
  const int lg = l >> 4, ll = l & 15;

  const f32x4 vzero = {0.f, 0.f, 0.f, 0.f};
  f32x4 acc[4][4];
#pragma unroll
  for (int i = 0; i < 4; ++i)
#pragma unroll
    for (int j = 0; j < 4; ++j) acc[i][j] = vzero;

  // staging: wave w owns rows [w*32, w*32+32); per call 8 rows (64 lanes x 16B)
  const u16* ga = A + (long)(bm + w * 32 + (l >> 3)) * K + (l & 7) * 8;
  const u16* gb = Bt + (long)(bn + w * 32 + (l >> 3)) * K + (l & 7) * 8;
  u16* la = a_lds + w * 32 * 64;
  u16* lb = b_lds + w * 32 * 64;
  const long rstep = (long)8 * K;

  for (int kt = 0; kt < K; kt += 64) {
    __syncthreads();                 // prior tile fully consumed
#pragma unroll
    for (int i = 0; i < 4; ++i) {
      gload16(ga + i * rstep, la + i * 512);
      gload16(gb + i * rstep, lb + i * 512);
    }
    ga += 64; gb += 64;
    __syncthreads();                 // drains vmcnt -> tile visible
#pragma unroll
    for (int kc = 0; kc < 2; ++kc) {
      short8 af[4], bfr[4];
#pragma unroll
      for (int mi = 0; mi < 4; ++mi)
        af[mi] = *(const short8*)(a_lds + (wm + mi * 16 + ll) * 64 + kc * 32 + lg * 8);
#pragma unroll
      for (int nb = 0; nb < 4; ++nb)
        bfr[nb] = *(const short8*)(b_lds + (wn + nb * 16 + ll) * 64 + kc * 32 + lg * 8);
#pragma unroll
      for (int mi = 0; mi < 4; ++mi)
#pragma unroll
        for (int nb = 0; nb < 4; ++nb)
          acc[mi][nb] = __builtin_amdgcn_mfma_f32_16x16x32_bf16(af[mi], bfr[nb],
                                                                acc[mi][nb], 0, 0, 0);
    }
  }
  const int rbase = bm + wm + lg * 4;
  const int cbase = bn + wn + ll;
#pragma unroll
  for (int mi = 0; mi < 4; ++mi)
#pragma unroll
    for (int nb = 0; nb < 4; ++nb)
#pragma unroll
      for (int r = 0; r < 4; ++r)
        C[(long)(rbase + mi * 16 + r) * N + cbase + nb * 16] = acc[mi][nb][r];
}

// ---------------- fused RoPE for q and k ----------------
__global__ __launch_bounds__(256) void k_rope(const float* __restrict__ qkv,
                                              const float* __restrict__ cosT,
                                              const float* __restrict__ sinT,
                                              u16* __restrict__ qb,
                                              u16* __restrict__ kb) {
  int j = threadIdx.x & 31;
  int pos = blockIdx.x * 8 + (threadIdx.x >> 5);
  int he = blockIdx.y;
  const float* row;
  float scale;
  u16* dst;
  if (he < 16) {
    row = qkv + (long)pos * 1536 + he * 64;
    scale = 0.18033688011112042f;          // 0.125 * log2(e): softmax in log2 domain
    dst = qb + (long)(he * SEQ + pos) * 64;
  } else {
    int kv = he - 16;
    row = qkv + (long)pos * 1536 + 1024 + kv * 64;
    scale = 1.0f;
    dst = kb + (long)(kv * SEQ + pos) * 64;
  }
  float x1 = row[2 * j], x2 = row[2 * j + 1];
  float c = cosT[(pos << 5) + j], s = sinT[(pos << 5) + j];
  float e  = (x1 * c - x2 * s) * scale;
  float od = (x1 * s + x2 * c) * scale;
  *(u32*)(dst + 2 * j) = (u32)f2bf(e) | ((u32)f2bf(od) << 16);
}

// ---------------- Flash attention: QBLK=128 (8 waves), KVBLK=64 ----------------
// grid: 512 blocks -> (h = b&15, qt = 31 - b>>4). ntiles = 2qt+2 (always even).
// q pre-scaled by 0.125*log2e. vT is [kv][d][seq]. 1 barrier per tile.
__global__ __launch_bounds__(512) void k_attn(const u16* __restrict__ q,
                                              const u16* __restrict__ kk,
                                              const u16* __restrict__ vT,
                                              u16* __restrict__ o) {
  const int b = blockIdx.x;
  const int h = b & 15;
  const int qt = 31 - (b >> 4);
  const int hkv = h >> 2;
  __shared__ __align__(16) u16 kbuf[2][64 * 64];
  __shared__ __align__(16) u16 vbuf[2][64 * 64];
  __shared__ __align__(16) u16 p_lds[8][16 * 64];
  const int t = threadIdx.x, w = t >> 6, l = t & 63;
  const int lg = l >> 4, ll = l & 15;
  const int q0 = qt * 128 + w * 16;
  const int grow = w * 16 + ll;          // block-relative q row owned by this lane
  const f32x4 vzero = {0.f, 0.f, 0.f, 0.f};

  short8 qa0 = *(const short8*)(q + ((long)(h * SEQ + q0 + ll) * 64 + lg * 8));
  short8 qa1 = *(const short8*)(q + ((long)(h * SEQ + q0 + ll) * 64 + 32 + lg * 8));

  f32x4 Oacc[4];
#pragma unroll
  for (int i = 0; i < 4; ++i) Oacc[i] = vzero;
  float mrun = -__builtin_inff();
  float lrun = 0.f;

  // staging: 512 threads, one uint4 K + one uint4 V each per tile
  const int sr = t >> 3, sc = t & 7;
  const u16* kptr = kk + (long)hkv * SEQ * 64 + sr * 64 + sc * 8;
  const u16* vptr = vT + (long)hkv * 64 * SEQ + (long)sr * SEQ + sc * 8;
  const int swz = sr * 8 + (sc ^ (sr & 7));
  uint4 kr = *(const uint4*)kptr, vr = *(const uint4*)vptr;
  kptr += 64 * 64; vptr += 64;

  u16* pw = p_lds[w];
  // hoisted byte offsets for swizzled b128 LDS reads
  const int g0 = (lg ^ (ll & 7)) << 4;
  const int g1 = ((lg ^ (ll & 7)) ^ 4) << 4;
  const int rbyte = ll * 128;
  const char* pwb = (const char*)pw + rbyte;
  const int pwoff = rbyte + (lg & 1) * 8 + ((((lg >> 1)) ^ (ll & 7)) << 4);
  const int ntiles = 2 * qt + 2;
  const int qt2 = 2 * qt;

#define TILE(BUF, KT)                                                          \
  {                                                                            \
    ((uint4*)kbuf[BUF])[swz] = kr;                                             \
    ((uint4*)vbuf[BUF])[swz] = vr;                                             \
    if ((KT) + 1 < ntiles) {                                                   \
      kr = *(const uint4*)kptr; vr = *(const uint4*)vptr;                      \
      kptr += 64 * 64; vptr += 64;                                             \
    }                                                                          \
    __syncthreads();                                                           \
    const char* kb_ = (const char*)kbuf[BUF] + rbyte;                          \
    const char* vb_ = (const char*)vbuf[BUF] + rbyte;                          \
    f32x4 S[4];                                                                \
    __builtin_amdgcn_s_setprio(1);                                             \
    _Pragma("unroll")                                                          \
    for (int st = 0; st < 4; ++st) {                                           \
      short8 ka0 = *(const short8*)(kb_ + st * 2048 + g0);                     \
      short8 ka1 = *(const short8*)(kb_ + st * 2048 + g1);                     \
      f32x4 z = vzero;                                                         \
      z = __builtin_amdgcn_mfma_f32_16x16x32_bf16(ka0, qa0, z, 0, 0, 0);       \
      z = __builtin_amdgcn_mfma_f32_16x16x32_bf16(ka1, qa1, z, 0, 0, 0);       \
      S[st] = z;                                                               \
    }                                                                          \
    __builtin_amdgcn_s_setprio(0);                                             \
    if ((KT) >= qt2) {                                                         \
      int kb0 = ((KT) - qt2) * 64;                                             \
      _Pragma("unroll")                                                        \
      for (int st = 0; st < 4; ++st)                                           \
        _Pragma("unroll")                                                      \
        for (int r = 0; r < 4; ++r)                                            \
          if (kb0 + st * 16 + lg * 4 + r > grow) S[st][r] = -__builtin_inff(); \
    }                                                                          \
    float ml = fmaxf(fmaxf(fmaxf(S[0][0], S[0][1]), fmaxf(S[0][2], S[0][3])),  \
                     fmaxf(fmaxf(S[1][0], S[1][1]), fmaxf(S[1][2], S[1][3]))); \
    ml = fmaxf(ml,                                                             \
        fmaxf(fmaxf(fmaxf(S[2][0], S[2][1]), fmaxf(S[2][2], S[2][3])),         \
              fmaxf(fmaxf(S[3][0], S[3][1]), fmaxf(S[3][2], S[3][3]))));       \
    ml = fmaxf(ml, __shfl_xor(ml, 16));                                        \
    ml = fmaxf(ml, __shfl_xor(ml, 32));                                        \
    if (__any(ml > mrun + 8.f)) {                                              \
      float mnew = fmaxf(mrun, ml);                                            \
      float alpha = exp2f(mrun - mnew);                                        \
      mrun = mnew;                                                             \
      lrun *= alpha;                                                           \
      float a0 = __shfl(alpha, (l & 48) | (lg * 4 + 0));                       \
      float a1 = __shfl(alpha, (l & 48) | (lg * 4 + 1));                       \
      float a2 = __shfl(alpha, (l & 48) | (lg * 4 + 2));                       \
      float a3 = __shfl(alpha, (l & 48) | (lg * 4 + 3));                       \
      _Pragma("unroll")                                                        \
      for (int nb = 0; nb < 4; ++nb) {                                         \
        Oacc[nb][0] *= a0; Oacc[nb][1] *= a1;                                  \
        Oacc[nb][2] *= a2; Oacc[nb][3] *= a3;                                  \
      }                                                                        \
    }                                                                          \
    float sl = 0.f;                                                            \
    _Pragma("unroll")                                                          \
    for (int st = 0; st < 4; ++st) {                                           \
      float p0 = exp2f(S[st][0] - mrun), p1 = exp2f(S[st][1] - mrun);          \
      float p2 = exp2f(S[st][2] - mrun), p3 = exp2f(S[st][3] - mrun);          \
      sl += (p0 + p1) + (p2 + p3);                                             \
      uint2 gg;                                                                \
      gg.x = (u32)f2bf(p0) | ((u32)f2bf(p1) << 16);                            \
      gg.y = (u32)f2bf(p2) | ((u32)f2bf(p3) << 16);                            \
      *(uint2*)((char*)pw + (pwoff ^ (st << 5))) = gg;                         \
    }                                                                          \
    sl += __shfl_xor(sl, 16);                                                  \
    sl += __shfl_xor(sl, 32);                                                  \
    lrun += sl;                                                                \
    asm volatile("" ::: "memory");   /* keep P-writes before PV reads */       \
    __builtin_amdgcn_s_setprio(1);                                             \
    _Pragma("unroll")                                                          \
    for (int kc = 0; kc < 2; ++kc) {                                           \
      short8 pa = *(const short8*)(pwb + (kc ? g1 : g0));                      \
      _Pragma("unroll")                                                        \
      for (int nb = 0; nb < 4; ++nb) {                                         \
        short8 vv = *(const short8*)(vb_ + nb * 2048 + (kc ? g1 : g0));        \
        Oacc[nb] = __builtin_amdgcn_mfma_f32_16x16x32_bf16(pa, vv, Oacc[nb],   \
                                                           0, 0, 0);           \
      }                                                                        \
    }                                                                          \
    __builtin_amdgcn_s_setprio(0);                                             \
  }

  for (int kt = 0; kt < ntiles; kt += 2) {
    TILE(0, kt)
    TILE(1, kt + 1)
  }
#undef TILE

  float i0 = 1.f / __shfl(lrun, (l & 48) | (lg * 4 + 0));
  float i1 = 1.f / __shfl(lrun, (l & 48) | (lg * 4 + 1));
  float i2 = 1.f / __shfl(lrun, (l & 48) | (lg * 4 + 2));
  float i3 = 1.f / __shfl(lrun, (l & 48) | (lg * 4 + 3));
#pragma unroll
  for (int nb = 0; nb < 4; ++nb) {
    int col = h * 64 + nb * 16 + ll;
    o[(long)(q0 + lg * 4 + 0) * 1024 + col] = f2bf(Oacc[nb][0] * i0);
    o[(long)(q0 + lg * 4 + 1) * 1024 + col] = f2bf(Oacc[nb][1] * i1);
    o[(long)(q0 + lg * 4 + 2) * 1024 + col] = f2bf(Oacc[nb][2] * i2);
    o[(long)(q0 + lg * 4 + 3) * 1024 + col] = f2bf(Oacc[nb][3] * i3);
  }
}

extern "C" void kernel_launch(void* const* d_in, const int* in_sizes, int n_in,
                              void* d_out, int out_size, void* d_ws, size_t ws_size,
                              hipStream_t stream) {
  const float* x  = (const float*)d_in[0];
  // d_in[1] = mask (causal, implicit) — unused
  const float* Wq = (const float*)d_in[2];
  const float* Wk = (const float*)d_in[3];
  const float* Wv = (const float*)d_in[4];
  const float* Wo = (const float*)d_in[5];
  float* out = (float*)d_out;

  char* ws = (char*)d_ws;
  float* qkv = (float*)(ws);                        // 4096*1536*4  = 25165824
  u16* xb    = (u16*)(ws + 25165824);               // 4096*1024*2  = 8388608 (reused as attn_out)
  u16* Wt    = (u16*)(ws + 33554432);               // 1536*1024*2  = 3145728
  u16* Wto   = (u16*)(ws + 36700160);               // 1024*1024*2  = 2097152
  u16* qb    = (u16*)(ws + 38797312);               // 16*4096*64*2 = 8388608
  u16* kb    = (u16*)(ws + 47185920);               // 4*4096*64*2  = 2097152
  u16* vb    = (u16*)(ws + 49283072);               // 4*64*4096*2  = 2097152
  float* cosT = (float*)(ws + 51380224);            // 4096*32*4    = 524288
  float* sinT = (float*)(ws + 51904512);            // 524288  -> total 52428800 B

  k_tables<<<512, 256, 0, stream>>>(cosT, sinT);
  k_convx<<<4096, 256, 0, stream>>>(x, xb);
  k_tconv<<<dim3(16, 16), 256, 0, stream>>>(Wq, 1024, Wt, 1024);
  k_tconv<<<dim3(4, 16), 256, 0, stream>>>(Wk, 256, Wt + 1024 * 1024, 1024);
  k_tconv<<<dim3(4, 16), 256, 0, stream>>>(Wv, 256, Wt + 1280 * 1024, 1024);
  k_tconv<<<dim3(16, 16), 256, 0, stream>>>(Wo, 1024, Wto, 1024);

  // qkv = x @ [Wq|Wk|Wv]
  k_gemm<<<dim3(32, 12), 256, 0, stream>>>(xb, Wt, qkv, 4096, 1536, 1024);

  // RoPE q+k fused (q scale folds 0.125*log2e)
  k_rope<<<dim3(512, 20), 256, 0, stream>>>(qkv, cosT, sinT, qb, kb);
  // v transposed: vb[kv][d][pos]
  k_tconv<<<dim3(4, 64), 256, 0, stream>>>(qkv + 1280, 1536, vb, 4096);

  k_attn<<<512, 512, 0, stream>>>(qb, kb, vb, xb);   // attn_out -> xb

  // out = attn_out @ Wo
  k_gemm<<<dim3(32, 8), 256, 0, stream>>>(xb, Wto, out, 4096, 1024, 1024);
}

// Round 4
// 172.239 us; speedup vs baseline: 1.5792x; 1.0027x over previous
//
#include <hip/hip_runtime.h>
#include <hip/hip_bf16.h>

typedef __attribute__((ext_vector_type(8))) short short8;   // 8 bf16 (4 VGPRs)
typedef __attribute__((ext_vector_type(4))) float f32x4;
typedef unsigned short u16;
typedef unsigned int u32;

#define SEQ 4096

__device__ __forceinline__ u16 f2bf(float f) {
  return __builtin_bit_cast(u16, __float2bfloat16(f));
}

// global -> LDS direct (16B/lane). LDS dest = wave-uniform base + lane*16.
typedef __attribute__((address_space(1))) u32 gas_u32;
typedef __attribute__((address_space(3))) u32 las_u32;
__device__ __forceinline__ void gload16(const u16* g, const u16* l) {
  __builtin_amdgcn_global_load_lds((gas_u32*)(unsigned long long)(const void*)g,
                                   (las_u32*)(u32)(unsigned long long)(const void*)l,
                                   16, 0, 0);
}

// ---------------- RoPE tables: cos/sin[pos][j], j=0..31 ----------------
__global__ __launch_bounds__(256) void k_tables(float* __restrict__ cosT,
                                                float* __restrict__ sinT) {
  int tid = blockIdx.x * 256 + threadIdx.x;   // SEQ*32
  int pos = tid >> 5, j = tid & 31;
  float theta = exp2f(-0.311430758895f * (float)j);  // 1000^(-j/32)
  float a = (float)pos * theta;
  float s, c;
  sincosf(a, &s, &c);
  cosT[tid] = c;
  sinT[tid] = s;
}

// ---------------- x fp32 -> bf16 (vectorized) ----------------
__global__ __launch_bounds__(256) void k_convx(const float* __restrict__ x,
                                               u16* __restrict__ xb) {
  int i = blockIdx.x * 256 + threadIdx.x;     // one float4 each
  float4 v = ((const float4*)x)[i];
  u32 lo = (u32)f2bf(v.x) | ((u32)f2bf(v.y) << 16);
  u32 hi = (u32)f2bf(v.z) | ((u32)f2bf(v.w) << 16);
  uint2 o; o.x = lo; o.y = hi;
  ((uint2*)xb)[i] = o;
}

// ---------------- transpose + convert: dst[c][r] = bf16(src[r][c]) ----------------
__global__ __launch_bounds__(256) void k_tconv(const float* __restrict__ src, int sstride,
                                               u16* __restrict__ dst, int dstride) {
  __shared__ float tile[64][65];
  int br = blockIdx.y * 64, bc = blockIdx.x * 64;
  int t = threadIdx.x;
#pragma unroll
  for (int i = 0; i < 16; ++i) {
    int idx = t + i * 256;
    int r = idx >> 6, c = idx & 63;
    tile[r][c] = src[(long)(br + r) * sstride + bc + c];
  }
  __syncthreads();
#pragma unroll
  for (int i = 0; i < 16; ++i) {
    int idx = t + i * 256;
    int cc = idx >> 6, rr = idx & 63;
    dst[(long)(bc + cc) * dstride + br + rr] = f2bf(tile[rr][cc]);
  }
}

// ---------------- GEMM: C[M][N] f32 = A[M][K]bf16 * Bt[N][K]bf16^T ----------------
// m97 structure, 128x64 tile for block-count: BK=64, linear LDS, gload_lds w16.
__global__ __launch_bounds__(256) void k_gemm(const u16* __restrict__ A,
                                              const u16* __restrict__ Bt,
                                              float* __restrict__ C,
                                              int M, int N, int K) {
  __shared__ __align__(16) u16 a_lds[128 * 64];
  __shared__ __align__(16) u16 b_lds[64 * 64];
  const int bm = blockIdx.x * 128, bn = blockIdx.y * 64;
  const int t = threadIdx.x;
  const int l = t & 63, w = t >> 6;
  const int wm = (w >> 1) * 64, wn = (w & 1) * 32;
  const int lg = l >> 4, ll = l & 15;

  const f32x4 vzero = {0.f, 0.f, 0.f, 0.f};
  f32x4 acc[4][2];
#pragma unroll
  for (int i = 0; i < 4; ++i)
#pragma unroll
    for (int j = 0; j < 2; ++j) acc[i][j] = vzero;

  // staging: wave w owns A rows [w*32,w*32+32) (4 gloads), B rows [w*16,w*16+16) (2)
  const u16* ga = A + (long)(bm + w * 32 + (l >> 3)) * K + (l & 7) * 8;
  const u16* gb = Bt + (long)(bn + w * 16 + (l >> 3)) * K + (l & 7) * 8;
  u16* la = a_lds + w * 32 * 64;
  u16* lb = b_lds + w * 16 * 64;
  const long rstep = (long)8 * K;

  for (int kt = 0; kt < K; kt += 64) {
    __syncthreads();                 // prior tile fully consumed
#pragma unroll
    for (int i = 0; i < 4; ++i) gload16(ga + i * rstep, la + i * 512);
#pragma unroll
    for (int i = 0; i < 2; ++i) gload16(gb + i * rstep, lb + i * 512);
    ga += 64; gb += 64;
    __syncthreads();                 // drains vmcnt -> tile visible
#pragma unroll
    for (int kc = 0; kc < 2; ++kc) {
      short8 af[4], bfr[2];
#pragma unroll
      for (int mi = 0; mi < 4; ++mi)
        af[mi] = *(const short8*)(a_lds + (wm + mi * 16 + ll) * 64 + kc * 32 + lg * 8);
#pragma unroll
      for (int nb = 0; nb < 2; ++nb)
        bfr[nb] = *(const short8*)(b_lds + (wn + nb * 16 + ll) * 64 + kc * 32 + lg * 8);
#pragma unroll
      for (int mi = 0; mi < 4; ++mi)
#pragma unroll
        for (int nb = 0; nb < 2; ++nb)
          acc[mi][nb] = __builtin_amdgcn_mfma_f32_16x16x32_bf16(af[mi], bfr[nb],
                                                                acc[mi][nb], 0, 0, 0);
    }
  }
  const int rbase = bm + wm + lg * 4;
  const int cbase = bn + wn + ll;
#pragma unroll
  for (int mi = 0; mi < 4; ++mi)
#pragma unroll
    for (int nb = 0; nb < 2; ++nb)
#pragma unroll
      for (int r = 0; r < 4; ++r)
        C[(long)(rbase + mi * 16 + r) * N + cbase + nb * 16] = acc[mi][nb][r];
}

// ---------------- fused RoPE for q and k ----------------
__global__ __launch_bounds__(256) void k_rope(const float* __restrict__ qkv,
                                              const float* __restrict__ cosT,
                                              const float* __restrict__ sinT,
                                              u16* __restrict__ qb,
                                              u16* __restrict__ kb) {
  int j = threadIdx.x & 31;
  int pos = blockIdx.x * 8 + (threadIdx.x >> 5);
  int he = blockIdx.y;
  const float* row;
  float scale;
  u16* dst;
  if (he < 16) {
    row = qkv + (long)pos * 1536 + he * 64;
    scale = 0.18033688011112042f;          // 0.125 * log2(e): softmax in log2 domain
    dst = qb + (long)(he * SEQ + pos) * 64;
  } else {
    int kv = he - 16;
    row = qkv + (long)pos * 1536 + 1024 + kv * 64;
    scale = 1.0f;
    dst = kb + (long)(kv * SEQ + pos) * 64;
  }
  float x1 = row[2 * j], x2 = row[2 * j + 1];
  float c = cosT[(pos << 5) + j], s = sinT[(pos << 5) + j];
  float e  = (x1 * c - x2 * s) * scale;
  float od = (x1 * s + x2 * c) * scale;
  *(u32*)(dst + 2 * j) = (u32)f2bf(e) | ((u32)f2bf(od) << 16);
}

// ---------------- Flash attention: QBLK=64 (4 waves), KVBLK=64, paired q-tiles ----
// 512 blocks; block (h, pr) does q-tiles {pr, 63-pr} -> uniform 65 key-tiles.
// q pre-scaled by 0.125*log2e. vT is [kv][d][seq]. 1 barrier per tile.
__global__ __launch_bounds__(256) void k_attn(const u16* __restrict__ q,
                                              const u16* __restrict__ kk,
                                              const u16* __restrict__ vT,
                                              u16* __restrict__ o) {
  const int b = blockIdx.x;
  const int h = ((b & 7) << 1) | ((b >> 3) & 1);  // same-XCD blocks share kv head
  const int pr = b >> 4;                           // 0..31
  const int hkv = h >> 2;
  __shared__ __align__(16) u16 kbuf[2][64 * 64];
  __shared__ __align__(16) u16 vbuf[2][64 * 64];
  __shared__ __align__(16) u16 p_lds[4][16 * 64];
  const int t = threadIdx.x, w = t >> 6, l = t & 63;
  const int lg = l >> 4, ll = l & 15;
  const int grow = w * 16 + ll;          // tile-relative q row owned by this lane
  const f32x4 vzero = {0.f, 0.f, 0.f, 0.f};

  const u16* kbase = kk + (long)hkv * SEQ * 64;
  const u16* vbase = vT + (long)hkv * 64 * SEQ;
  const int sr0 = t >> 3, sc = t & 7, sr1 = sr0 + 32;
  const int swz0 = sr0 * 8 + (sc ^ (sr0 & 7));
  const int swz1 = sr1 * 8 + (sc ^ (sr1 & 7));

  u16* pw = p_lds[w];
  const int g0 = (lg ^ (ll & 7)) << 4;
  const int g1 = ((lg ^ (ll & 7)) ^ 4) << 4;
  const int rbyte = ll * 128;
  const char* pwb = (const char*)pw + rbyte;
  const int pwoff = rbyte + (lg & 1) * 8 + (((lg >> 1) ^ (ll & 7)) << 4);

  uint4 kr0, kr1, vr0, vr1;
#define ISSUE(KT)                                                            \
  {                                                                          \
    long kc0 = (long)(KT) * 64;                                              \
    kr0 = *(const uint4*)(kbase + (kc0 + sr0) * 64 + sc * 8);                \
    kr1 = *(const uint4*)(kbase + (kc0 + sr1) * 64 + sc * 8);                \
    vr0 = *(const uint4*)(vbase + (long)sr0 * SEQ + kc0 + sc * 8);           \
    vr1 = *(const uint4*)(vbase + (long)sr1 * SEQ + kc0 + sc * 8);           \
  }

  ISSUE(0);
  int buf = 0;   // parity carried across segments (keeps 1-barrier scheme race-free)

  for (int seg = 0; seg < 2; ++seg) {
    const int qt = seg ? (63 - pr) : pr;
    const int q0 = qt * 64 + w * 16;
    short8 qa0 = *(const short8*)(q + ((long)(h * SEQ + q0 + ll) * 64 + lg * 8));
    short8 qa1 = *(const short8*)(q + ((long)(h * SEQ + q0 + ll) * 64 + 32 + lg * 8));

    f32x4 Oacc[4] = {vzero, vzero, vzero, vzero};
    float mrun = -__builtin_inff();
    float lrun = 0.f;

    for (int kt = 0; kt <= qt; ++kt) {
      u16* kc_ = kbuf[buf];
      u16* vc_ = vbuf[buf];
      buf ^= 1;
      ((uint4*)kc_)[swz0] = kr0;
      ((uint4*)kc_)[swz1] = kr1;
      ((uint4*)vc_)[swz0] = vr0;
      ((uint4*)vc_)[swz1] = vr1;
      if (kt < qt) { ISSUE(kt + 1); }
      else if (seg == 0) { ISSUE(0); }   // cross-segment prefetch
      __syncthreads();

      const char* kb_ = (const char*)kc_ + rbyte;
      const char* vb_ = (const char*)vc_ + rbyte;
      f32x4 S[4];
      __builtin_amdgcn_s_setprio(1);
#pragma unroll
      for (int st = 0; st < 4; ++st) {
        short8 ka0 = *(const short8*)(kb_ + st * 2048 + g0);
        short8 ka1 = *(const short8*)(kb_ + st * 2048 + g1);
        f32x4 z = vzero;
        z = __builtin_amdgcn_mfma_f32_16x16x32_bf16(ka0, qa0, z, 0, 0, 0);
        z = __builtin_amdgcn_mfma_f32_16x16x32_bf16(ka1, qa1, z, 0, 0, 0);
        S[st] = z;
      }
      __builtin_amdgcn_s_setprio(0);

      if (kt == qt) {   // diagonal tile: causal mask (tile-relative)
#pragma unroll
        for (int st = 0; st < 4; ++st)
#pragma unroll
          for (int r = 0; r < 4; ++r)
            if (st * 16 + lg * 4 + r > grow) S[st][r] = -__builtin_inff();
      }

      float ml = fmaxf(fmaxf(fmaxf(S[0][0], S[0][1]), fmaxf(S[0][2], S[0][3])),
                       fmaxf(fmaxf(S[1][0], S[1][1]), fmaxf(S[1][2], S[1][3])));
      ml = fmaxf(ml,
          fmaxf(fmaxf(fmaxf(S[2][0], S[2][1]), fmaxf(S[2][2], S[2][3])),
                fmaxf(fmaxf(S[3][0], S[3][1]), fmaxf(S[3][2], S[3][3]))));
      ml = fmaxf(ml, __shfl_xor(ml, 16));
      ml = fmaxf(ml, __shfl_xor(ml, 32));

      if (__any(ml > mrun + 8.f)) {   // defer-max
        float mnew = fmaxf(mrun, ml);
        float alpha = exp2f(mrun - mnew);
        mrun = mnew;
        lrun *= alpha;
        float a0 = __shfl(alpha, (l & 48) | (lg * 4 + 0));
        float a1 = __shfl(alpha, (l & 48) | (lg * 4 + 1));
        float a2 = __shfl(alpha, (l & 48) | (lg * 4 + 2));
        float a3 = __shfl(alpha, (l & 48) | (lg * 4 + 3));
#pragma unroll
        for (int nb = 0; nb < 4; ++nb) {
          Oacc[nb][0] *= a0; Oacc[nb][1] *= a1;
          Oacc[nb][2] *= a2; Oacc[nb][3] *= a3;
        }
      }

      float sl = 0.f;
#pragma unroll
      for (int st = 0; st < 4; ++st) {
        float p0 = exp2f(S[st][0] - mrun), p1 = exp2f(S[st][1] - mrun);
        float p2 = exp2f(S[st][2] - mrun), p3 = exp2f(S[st][3] - mrun);
        sl += (p0 + p1) + (p2 + p3);
        uint2 gg;
        gg.x = (u32)f2bf(p0) | ((u32)f2bf(p1) << 16);
        gg.y = (u32)f2bf(p2) | ((u32)f2bf(p3) << 16);
        *(uint2*)((char*)pw + (pwoff ^ (st << 5))) = gg;
      }
      sl += __shfl_xor(sl, 16);
      sl += __shfl_xor(sl, 32);
      lrun += sl;

      asm volatile("" ::: "memory");   // keep P-writes before PV reads
      __builtin_amdgcn_s_setprio(1);
#pragma unroll
      for (int kc = 0; kc < 2; ++kc) {
        short8 pa = *(const short8*)(pwb + (kc ? g1 : g0));
#pragma unroll
        for (int nb = 0; nb < 4; ++nb) {
          short8 vv = *(const short8*)(vb_ + nb * 2048 + (kc ? g1 : g0));
          Oacc[nb] = __builtin_amdgcn_mfma_f32_16x16x32_bf16(pa, vv, Oacc[nb],
                                                             0, 0, 0);
        }
      }
      __builtin_amdgcn_s_setprio(0);
    }

    float i0 = 1.f / __shfl(lrun, (l & 48) | (lg * 4 + 0));
    float i1 = 1.f / __shfl(lrun, (l & 48) | (lg * 4 + 1));
    float i2 = 1.f / __shfl(lrun, (l & 48) | (lg * 4 + 2));
    float i3 = 1.f / __shfl(lrun, (l & 48) | (lg * 4 + 3));
#pragma unroll
    for (int nb = 0; nb < 4; ++nb) {
      int col = h * 64 + nb * 16 + ll;
      o[(long)(q0 + lg * 4 + 0) * 1024 + col] = f2bf(Oacc[nb][0] * i0);
      o[(long)(q0 + lg * 4 + 1) * 1024 + col] = f2bf(Oacc[nb][1] * i1);
      o[(long)(q0 + lg * 4 + 2) * 1024 + col] = f2bf(Oacc[nb][2] * i2);
      o[(long)(q0 + lg * 4 + 3) * 1024 + col] = f2bf(Oacc[nb][3] * i3);
    }
  }
#undef ISSUE
}

extern "C" void kernel_launch(void* const* d_in, const int* in_sizes, int n_in,
                              void* d_out, int out_size, void* d_ws, size_t ws_size,
                              hipStream_t stream) {
  const float* x  = (const float*)d_in[0];
  // d_in[1] = mask (causal, implicit) — unused
  const float* Wq = (const float*)d_in[2];
  const float* Wk = (const float*)d_in[3];
  const float* Wv = (const float*)d_in[4];
  const float* Wo = (const float*)d_in[5];
  float* out = (float*)d_out;

  char* ws = (char*)d_ws;
  float* qkv = (float*)(ws);                        // 4096*1536*4  = 25165824
  u16* xb    = (u16*)(ws + 25165824);               // 4096*1024*2  = 8388608 (reused as attn_out)
  u16* Wt    = (u16*)(ws + 33554432);               // 1536*1024*2  = 3145728
  u16* Wto   = (u16*)(ws + 36700160);               // 1024*1024*2  = 2097152
  u16* qb    = (u16*)(ws + 38797312);               // 16*4096*64*2 = 8388608
  u16* kb    = (u16*)(ws + 47185920);               // 4*4096*64*2  = 2097152
  u16* vb    = (u16*)(ws + 49283072);               // 4*64*4096*2  = 2097152
  float* cosT = (float*)(ws + 51380224);            // 4096*32*4    = 524288
  float* sinT = (float*)(ws + 51904512);            // 524288  -> total 52428800 B

  k_tables<<<512, 256, 0, stream>>>(cosT, sinT);
  k_convx<<<4096, 256, 0, stream>>>(x, xb);
  k_tconv<<<dim3(16, 16), 256, 0, stream>>>(Wq, 1024, Wt, 1024);
  k_tconv<<<dim3(4, 16), 256, 0, stream>>>(Wk, 256, Wt + 1024 * 1024, 1024);
  k_tconv<<<dim3(4, 16), 256, 0, stream>>>(Wv, 256, Wt + 1280 * 1024, 1024);
  k_tconv<<<dim3(16, 16), 256, 0, stream>>>(Wo, 1024, Wto, 1024);

  // qkv = x @ [Wq|Wk|Wv]
  k_gemm<<<dim3(32, 24), 256, 0, stream>>>(xb, Wt, qkv, 4096, 1536, 1024);

  // RoPE q+k fused (q scale folds 0.125*log2e)
  k_rope<<<dim3(512, 20), 256, 0, stream>>>(qkv, cosT, sinT, qb, kb);
  // v transposed: vb[kv][d][pos]
  k_tconv<<<dim3(4, 64), 256, 0, stream>>>(qkv + 1280, 1536, vb, 4096);

  k_attn<<<512, 256, 0, stream>>>(qb, kb, vb, xb);   // attn_out -> xb

  // out = attn_out @ Wo
  k_gemm<<<dim3(32, 16), 256, 0, stream>>>(xb, Wto, out, 4096, 1024, 1024);
}